// Round 10
// baseline (46.480 us; speedup 1.0000x reference)
//
#include <hip/hip_runtime.h>
#include <math.h>
#include <stdint.h>

#define NTOK 8192
#define HID  4096
#define NEXP 64
#define TOPK 8

typedef float    f32x4 __attribute__((ext_vector_type(4)));
typedef _Float16 f16x8 __attribute__((ext_vector_type(8)));

// ws layout:
//   [0, 1MB)   : wsW — 32 ktiles (128 k each) x 32KB. Tile kt stores, at linear
//                16B-entry e (0..2047):  region hi (e<1024) / lo (e>=1024);
//                within region: r = e>>4, sl = e&15, holding W chunk c = sl ^ (r&7)
//                (8 f16 = k [kt*128 + c*8, +8) of expert r, x2048 scale).
//                This is exactly the LDS image k1 wants -> gll sources are LINEAR.
//   [1MB, 9MB) : logits partials [4][NTOK][64] f32 (x2048 scale)

__device__ __forceinline__ void cvt_hilo(f32x4 a, f32x4 b, f16x8& hi, f16x8& lo)
{
    float x[8] = {a.x, a.y, a.z, a.w, b.x, b.y, b.z, b.w};
#pragma unroll
    for (int j = 0; j < 8; ++j) {
        const _Float16 h = (_Float16)x[j];
        hi[j] = h;
        lo[j] = (_Float16)(x[j] - (float)h);
    }
}

__device__ __forceinline__ void gll16(const void* g, void* l) {
    __builtin_amdgcn_global_load_lds(
        (const __attribute__((address_space(1))) uint32_t*)g,
        (__attribute__((address_space(3))) uint32_t*)l, 16, 0, 0);
}

// ---------------------------------------------------------------------
// k0: W fp32 -> pre-swizzled f16 hi/lo ktiles (x2048). 128 blocks x 256.
// thread -> (kt, r, sl); data chunk c = sl ^ (r&7).
// ---------------------------------------------------------------------
__global__ __launch_bounds__(256)
void k0_wsplit(const float* __restrict__ W, char* __restrict__ wsW)
{
    const int gidx = blockIdx.x * 256 + threadIdx.x;   // 0..32767
    const int kt = gidx >> 10;          // 32 tiles of 128 k
    const int r  = (gidx >> 4) & 63;
    const int sl = gidx & 15;
    const int c  = sl ^ (r & 7);

    const float* src = W + (size_t)r * HID + kt * 128 + c * 8;
    const f32x4 w0 = *(const f32x4*)src;
    const f32x4 w1 = *(const f32x4*)(src + 4);
    f16x8 hi, lo;
    cvt_hilo(w0 * 2048.0f, w1 * 2048.0f, hi, lo);

    f16x8* tile = (f16x8*)(wsW + (size_t)kt * 32768);
    tile[r * 16 + sl]        = hi;      // entries 0..1023
    tile[1024 + r * 16 + sl] = lo;      // entries 1024..2047
}

// ---------------------------------------------------------------------
// k1: partial logits (x2048). 512 blocks x 256 thr (4 waves token-split,
// block k-quarter m). 8 ktiles of 128k, double-buffered 32KB LDS tiles.
// T3/T4 schedule: per phase = raw s_barrier -> STAGE(next) -> counted
// s_waitcnt vmcnt(N) (A-ring + new gll stay IN FLIGHT across barriers)
// -> 4 MFMA steps.  vmcnt(0) only in the last phase.
// ---------------------------------------------------------------------
#define AL(SET, S) do { const float* _p = ha + (S) * 32;                      \
    SET##0 = *(const f32x4*)_p; SET##1 = *(const f32x4*)(_p + 4); } while (0)
#define ALG(SET, S) do { if ((S) < 32) AL(SET, S); } while (0)

#define STEPU(SET, KS) do {                                                   \
    f16x8 _ah, _al; cvt_hilo(SET##0, SET##1, _ah, _al);                       \
    _Pragma("unroll")                                                         \
    for (int _e4 = 0; _e4 < 4; ++_e4) {                                       \
        const int _r  = _e4 * 16 + lr;                                        \
        const int _sl = ((KS) * 4 + kg) ^ (lr & 7);                           \
        const f16x8 _bh = *(const f16x8*)&bt[(_r * 16 + _sl) * 8];            \
        const f16x8 _bl = *(const f16x8*)&bt[8192 + (_r * 16 + _sl) * 8];     \
        accH[_e4] = __builtin_amdgcn_mfma_f32_16x16x32_f16(_ah, _bh, accH[_e4], 0, 0, 0); \
        accM[_e4] = __builtin_amdgcn_mfma_f32_16x16x32_f16(_ah, _bl, accM[_e4], 0, 0, 0); \
        accL[_e4] = __builtin_amdgcn_mfma_f32_16x16x32_f16(_al, _bh, accL[_e4], 0, 0, 0); \
    } } while (0)

#define STAGE(KT, BUF) do {                                                   \
    const char* _s = wsrc + (KT) * 32768;                                     \
    _Pragma("unroll")                                                         \
    for (int _t = 0; _t < 8; ++_t)                                            \
        gll16(_s + _t * 4096, (void*)&BT[BUF][_t * 2048 + tid * 8]);          \
} while (0)

// counted wait: drain down to N outstanding vmem ops, then pin scheduling
#define VMW(N) do {                                                           \
    asm volatile("s_waitcnt vmcnt(" #N ")" ::: "memory");                     \
    __builtin_amdgcn_sched_barrier(0);                                        \
} while (0)

#define KTILE(KT, VN, SA, SB, SC, SD) do {                                    \
    __builtin_amdgcn_s_barrier();       /* prev phase's reads all retired */  \
    if ((KT) < 7) STAGE((KT) + 1, ((KT) & 1) ^ 1);                            \
    VMW(VN);                            /* waits only STAGE(KT)'s 8 gll   */  \
    const _Float16* bt = &BT[(KT) & 1][0];                                    \
    STEPU(SA, 0); ALG(SA, (KT) * 4 + 8);                                      \
    STEPU(SB, 1); ALG(SB, (KT) * 4 + 9);                                      \
    STEPU(SC, 2); ALG(SC, (KT) * 4 + 10);                                     \
    STEPU(SD, 3); ALG(SD, (KT) * 4 + 11);                                     \
} while (0)

__global__ __launch_bounds__(256, 2)
void k1_partial(const float* __restrict__ Hm, const char* __restrict__ wsW,
                float* __restrict__ lgp)
{
    __shared__ _Float16 BT[2][16384];   // 2 x 32KB ktile images

    const int tid  = threadIdx.x;
    const int wave = tid >> 6;
    const int l    = tid & 63;
    const int lr   = l & 15;            // A row (token) / B col (expert) in tile
    const int kg   = l >> 4;            // k-subgroup (8 consecutive k)
    const int tg   = blockIdx.x >> 2;
    const int m    = blockIdx.x & 3;
    const int tok0 = tg * 64 + wave * 16;

    const float* ha   = Hm + (size_t)(tok0 + lr) * HID + m * 1024 + kg * 8;
    const char*  wsrc = wsW + (size_t)m * 8 * 32768 + tid * 16;

    f32x4 accH[4], accM[4], accL[4];
#pragma unroll
    for (int e = 0; e < 4; ++e) {
        accH[e] = (f32x4)(0.0f); accM[e] = (f32x4)(0.0f); accL[e] = (f32x4)(0.0f);
    }

    // prologue: stage ktile 0 (oldest vmem ops), then fill depth-8 A ring
    STAGE(0, 0);
    f32x4 Aa0, Aa1, Ab0, Ab1, Ac0, Ac1, Ad0, Ad1;
    f32x4 Ae0, Ae1, Af0, Af1, Ag0, Ag1, Ah0, Ah1;
    AL(Aa, 0); AL(Ab, 1); AL(Ac, 2); AL(Ad, 3);
    AL(Ae, 4); AL(Af, 5); AL(Ag, 6); AL(Ah, 7);

    // vmcnt N per phase = ops newer than the gll batch we must drain:
    //   phase 0: 16 A-prologue + 8 gll_1            = 24
    //   phase 1..6: 8 A (prev phase) + 8 gll_next   = 16
    //   phase 7: 0 (final; also drains everything)
    KTILE(0, 24, Aa, Ab, Ac, Ad);
    KTILE(1, 16, Ae, Af, Ag, Ah);
    KTILE(2, 16, Aa, Ab, Ac, Ad);
    KTILE(3, 16, Ae, Af, Ag, Ah);
    KTILE(4, 16, Aa, Ab, Ac, Ad);
    KTILE(5, 16, Ae, Af, Ag, Ah);
    KTILE(6, 16, Aa, Ab, Ac, Ad);
    KTILE(7,  0, Ae, Af, Ag, Ah);

    // merge banks, write partial slice. C/D: col=lane&15, row=(lane>>4)*4+r.
    float* wsw = lgp + ((size_t)m * NTOK + tok0) * 64;
#pragma unroll
    for (int e4 = 0; e4 < 4; ++e4) {
        const f32x4 a = accH[e4] + accM[e4] + accL[e4];
#pragma unroll
        for (int r = 0; r < 4; ++r)
            wsw[(kg * 4 + r) * 64 + e4 * 16 + lr] = a[r];
    }
}

// ---------------------------------------------------------------------
// k2: fixed-order 4-slice reduce + softmax + top-8 rank-count.
// 2048 blocks x 256 thr; 1 token per wave (proven form).
// ---------------------------------------------------------------------
__global__ __launch_bounds__(256)
void k2_finish(const float* __restrict__ lgp, float* __restrict__ out)
{
    __shared__ __align__(16) float sc[4][64];
    const int tid  = threadIdx.x;
    const int wave = tid >> 6;
    const int lane = tid & 63;
    float* outw = out;
    float* outi = out + (size_t)NTOK * TOPK;

    const int tok = blockIdx.x * 4 + wave;
    const float* p = lgp + (size_t)tok * 64 + lane;
    const float lgv = ((p[0] + p[(size_t)NTOK * 64])
                     + (p[(size_t)2 * NTOK * 64] + p[(size_t)3 * NTOK * 64]))
                     * (1.0f / 2048.0f);

    float mx = lgv;
#pragma unroll
    for (int off = 32; off; off >>= 1) mx = fmaxf(mx, __shfl_xor(mx, off));
    const float pv = expf(lgv - mx);
    float ss = pv;
#pragma unroll
    for (int off = 32; off; off >>= 1) ss += __shfl_xor(ss, off);
    ss = __shfl(ss, 0);                 // identical denominator on all lanes
    const float sval = pv / ss;

    sc[wave][lane] = sval;
    __syncthreads();

    int rank = 0;
#pragma unroll
    for (int j4 = 0; j4 < 16; ++j4) {
        const f32x4 v = *(const f32x4*)&sc[wave][j4 * 4];
#pragma unroll
        for (int u = 0; u < 4; ++u) {
            const int j = j4 * 4 + u;
            rank += (v[u] > sval || (v[u] == sval && j < lane)) ? 1 : 0;
        }
    }
    if (rank < TOPK) {
        outw[(size_t)tok * TOPK + rank] = sval;
        outi[(size_t)tok * TOPK + rank] = (float)lane;
    }
}

extern "C" void kernel_launch(void* const* d_in, const int* in_sizes, int n_in,
                              void* d_out, int out_size, void* d_ws, size_t ws_size,
                              hipStream_t stream) {
    (void)in_sizes; (void)n_in; (void)out_size; (void)ws_size;
    const float* h = (const float*)d_in[0];   // [8192, 4096] fp32
    const float* w = (const float*)d_in[1];   // [64, 4096]  fp32
    float* out = (float*)d_out;

    char*  wsW = (char*)d_ws;                         // 1 MB swizzled f16 W tiles
    float* lgp = (float*)((char*)d_ws + (1 << 20));   // 8 MB logits partials

    k0_wsplit<<<128, 256, 0, stream>>>(w, wsW);
    k1_partial<<<512, 256, 0, stream>>>(h, wsW, lgp);
    k2_finish<<<NTOK / 4, 256, 0, stream>>>(lgp, out);
}